// Round 3
// baseline (1039.871 us; speedup 1.0000x reference)
//
#include <hip/hip_runtime.h>
#include <hip/hip_bf16.h>
#include <cstdint>

#define HD 1024
#define ID 4096
#define NE 8
#define NTOK 4096
#define NASS 8192

typedef unsigned short u16;
typedef __attribute__((ext_vector_type(8))) __bf16 bf16x8;
typedef __attribute__((ext_vector_type(4))) float f32x4;

__device__ __forceinline__ void async16(void* lds, const void* g) {
  __builtin_amdgcn_global_load_lds(
      (const __attribute__((address_space(1))) uint32_t*)g,
      (__attribute__((address_space(3))) uint32_t*)lds, 16, 0, 0);
}

__device__ __forceinline__ u16 f2b(float f) {
  __bf16 h = (__bf16)f;
  return __builtin_bit_cast(u16, h);
}

__device__ __forceinline__ bf16x8 cvt8(const float* p) {
  const float4* q = (const float4*)p;
  float4 a = q[0], b = q[1];
  bf16x8 v;
  v[0] = (__bf16)a.x; v[1] = (__bf16)a.y; v[2] = (__bf16)a.z; v[3] = (__bf16)a.w;
  v[4] = (__bf16)b.x; v[5] = (__bf16)b.y; v[6] = (__bf16)b.z; v[7] = (__bf16)b.w;
  return v;
}

__device__ __forceinline__ void membar() { asm volatile("" ::: "memory"); }

// ---- prep: x->xb bf16, gate->wg bf16, up->wu bf16 (one BW-bound pass) ----
__global__ void k_pre(const float* __restrict__ x, const float* __restrict__ gate,
                      const float* __restrict__ up, u16* __restrict__ xb,
                      u16* __restrict__ wg, u16* __restrict__ wu) {
  int bid = blockIdx.x, t = threadIdx.x;
  if (bid < 2048) {
    size_t i8 = ((size_t)bid * 256 + t) * 8;
    *(bf16x8*)(xb + i8) = cvt8(x + i8);
  } else if (bid < 18432) {
    size_t i8 = ((size_t)(bid - 2048) * 256 + t) * 8;
    *(bf16x8*)(wg + i8) = cvt8(gate + i8);
  } else {
    size_t i8 = ((size_t)(bid - 18432) * 256 + t) * 8;
    *(bf16x8*)(wu + i8) = cvt8(up + i8);
  }
}

// ---- fused count + scan + place (single block); tokl stores assignment id ----
__global__ void k_meta(const int* __restrict__ eidx, int* __restrict__ offsets,
                       int* __restrict__ tokl) {
  __shared__ int cnt[NE], offs_s[NE + 1], cur[NE];
  int t = threadIdx.x;
  if (t < NE) cnt[t] = 0;
  __syncthreads();
  for (int i = t; i < NASS; i += 1024) atomicAdd(&cnt[eidx[i]], 1);
  __syncthreads();
  if (t == 0) {
    int s = 0;
    for (int e = 0; e < NE; ++e) { offs_s[e] = s; s += cnt[e]; }
    offs_s[NE] = s;
  }
  if (t < NE) cur[t] = 0;
  __syncthreads();
  for (int i = t; i < NASS; i += 1024) {
    int e = eidx[i];
    int p = atomicAdd(&cur[e], 1);
    tokl[offs_s[e] + p] = i;   // full assignment id (token = i>>1)
  }
  if (t <= NE) offsets[t] = offs_s[t];
}

// ---- GEMM1: interm = silu(X@G^T)*(X@U^T); dbuf 2-phase counted-vmcnt;
//      grid-fused with down-proj fp32->bf16 conversion (every 3rd block) ----
__global__ __launch_bounds__(256) void k_g1(
    const u16* __restrict__ xb, const u16* __restrict__ wg, const u16* __restrict__ wu,
    const float* __restrict__ down, u16* __restrict__ wd,
    const int* __restrict__ offsets, const int* __restrict__ tokl,
    u16* __restrict__ interm) {
  const int bid = blockIdx.x;
  const int r3 = bid % 3;
  if (r3 == 1) {                      // wd conversion, hidden under gemm compute
    size_t i8 = ((size_t)(bid / 3) * 256 + threadIdx.x) * 8;
    *(bf16x8*)(wd + i8) = cvt8(down + i8);
    return;
  }
  const int gid = (bid / 3) * 2 + (r3 >> 1);
  const int m = gid & 63, n = (gid >> 6) & 63, e = gid >> 12;
  const int offs = offsets[e];
  const int Me = offsets[e + 1] - offs;
  const int m0 = m * 128;
  if (m0 >= Me) return;
  const int n0 = n * 64;
  const int t = threadIdx.x, lane = t & 63, wv = t >> 6;
  const int wm = wv & 1, wn = wv >> 1;

  __shared__ __align__(16) u16 As[2][128 * 64];
  __shared__ __align__(16) u16 Bg[2][64 * 64];
  __shared__ __align__(16) u16 Bu[2][64 * 64];

  const u16* asrc[4];
#pragma unroll
  for (int p = 0; p < 4; ++p) {
    int c = p * 256 + t;
    int r = c >> 3, c8 = c & 7;
    int row = m0 + r; if (row > Me - 1) row = Me - 1;
    asrc[p] = xb + (size_t)(tokl[offs + row] >> 1) * HD + c8 * 8;
  }
  const u16 *bgsrc[2], *busrc[2];
#pragma unroll
  for (int q = 0; q < 2; ++q) {
    int c = q * 256 + t;
    int r = c >> 3, c8 = c & 7;
    size_t boff = ((size_t)e * ID + n0 + r) * HD + c8 * 8;
    bgsrc[q] = wg + boff;
    busrc[q] = wu + boff;
  }

#define STAGE1(b, ks)                                                          \
  {                                                                            \
    _Pragma("unroll") for (int p = 0; p < 4; ++p)                              \
        async16((char*)As[b] + (p * 256 + wv * 64) * 16, asrc[p] + (ks) * 64); \
    _Pragma("unroll") for (int q = 0; q < 2; ++q) {                            \
      async16((char*)Bg[b] + (q * 256 + wv * 64) * 16, bgsrc[q] + (ks) * 64);  \
      async16((char*)Bu[b] + (q * 256 + wv * 64) * 16, busrc[q] + (ks) * 64);  \
    }                                                                          \
  }

  f32x4 accg[4][2], accu[4][2];
#pragma unroll
  for (int mi = 0; mi < 4; ++mi)
#pragma unroll
    for (int ni = 0; ni < 2; ++ni) {
      accg[mi][ni] = (f32x4){0.f, 0.f, 0.f, 0.f};
      accu[mi][ni] = (f32x4){0.f, 0.f, 0.f, 0.f};
    }

  STAGE1(0, 0);
  const int lrow = lane & 15, lk = (lane >> 4) * 8;
#pragma unroll 1
  for (int ks = 0; ks < 16; ++ks) {
    const int curb = ks & 1;
    if (ks < 15) {
      STAGE1(curb ^ 1, ks + 1);
      asm volatile("s_waitcnt vmcnt(8)" ::: "memory");   // wait current tile only
    } else {
      asm volatile("s_waitcnt vmcnt(0)" ::: "memory");
    }
    membar(); __builtin_amdgcn_s_barrier(); membar();
    const u16* A = As[curb];
    const u16* G = Bg[curb];
    const u16* U = Bu[curb];
#pragma unroll
    for (int kk = 0; kk < 2; ++kk) {
      bf16x8 af[4], bg[2], bu[2];
#pragma unroll
      for (int mi = 0; mi < 4; ++mi)
        af[mi] = *(const bf16x8*)&A[(wm * 64 + mi * 16 + lrow) * 64 + kk * 32 + lk];
#pragma unroll
      for (int ni = 0; ni < 2; ++ni) {
        bg[ni] = *(const bf16x8*)&G[(wn * 32 + ni * 16 + lrow) * 64 + kk * 32 + lk];
        bu[ni] = *(const bf16x8*)&U[(wn * 32 + ni * 16 + lrow) * 64 + kk * 32 + lk];
      }
#pragma unroll
      for (int mi = 0; mi < 4; ++mi)
#pragma unroll
        for (int ni = 0; ni < 2; ++ni) {
          accg[mi][ni] = __builtin_amdgcn_mfma_f32_16x16x32_bf16(af[mi], bg[ni], accg[mi][ni], 0, 0, 0);
          accu[mi][ni] = __builtin_amdgcn_mfma_f32_16x16x32_bf16(af[mi], bu[ni], accu[mi][ni], 0, 0, 0);
        }
    }
    membar(); __builtin_amdgcn_s_barrier(); membar();  // protect buffer for next stage
  }

#pragma unroll
  for (int mi = 0; mi < 4; ++mi) {
    int rb = wm * 64 + mi * 16 + (lane >> 4) * 4;
#pragma unroll
    for (int ni = 0; ni < 2; ++ni) {
      int col = n0 + wn * 32 + ni * 16 + (lane & 15);
#pragma unroll
      for (int j = 0; j < 4; ++j) {
        int row = m0 + rb + j;
        if (row < Me) {
          float g = accg[mi][ni][j], u = accu[mi][ni][j];
          float s = g / (1.f + __expf(-g));
          interm[(size_t)(offs + row) * ID + col] = f2b(s * u);
        }
      }
    }
  }
#undef STAGE1
}

// ---- GEMM2: buf[aid,:] = interm @ D^T (raw, unweighted); dbuf 2-phase ----
__global__ __launch_bounds__(256) void k_g2(
    const u16* __restrict__ interm, const u16* __restrict__ wd,
    const int* __restrict__ offsets, const int* __restrict__ tokl,
    float* __restrict__ buf) {
  const int e = blockIdx.z;
  const int offs = offsets[e];
  const int Me = offsets[e + 1] - offs;
  const int m0 = blockIdx.y * 128;
  if (m0 >= Me) return;
  const int n0 = blockIdx.x * 128;
  const int t = threadIdx.x, lane = t & 63, wv = t >> 6;
  const int wm = wv & 1, wn = wv >> 1;

  __shared__ __align__(16) u16 As[2][128 * 64];
  __shared__ __align__(16) u16 Bs[2][128 * 64];

  const u16* asrc[4];
#pragma unroll
  for (int p = 0; p < 4; ++p) {
    int c = p * 256 + t;
    int r = c >> 3, c8 = c & 7;
    int row = m0 + r; if (row > Me - 1) row = Me - 1;
    asrc[p] = interm + (size_t)(offs + row) * ID + c8 * 8;
  }
  const u16* bsrc[4];
#pragma unroll
  for (int p = 0; p < 4; ++p) {
    int c = p * 256 + t;
    int r = c >> 3, c8 = c & 7;
    bsrc[p] = wd + ((size_t)e * HD + n0 + r) * ID + c8 * 8;
  }

#define STAGE2(b, ks)                                                          \
  {                                                                            \
    _Pragma("unroll") for (int p = 0; p < 4; ++p) {                            \
      async16((char*)As[b] + (p * 256 + wv * 64) * 16, asrc[p] + (ks) * 64);   \
      async16((char*)Bs[b] + (p * 256 + wv * 64) * 16, bsrc[p] + (ks) * 64);   \
    }                                                                          \
  }

  f32x4 acc[4][4];
#pragma unroll
  for (int mi = 0; mi < 4; ++mi)
#pragma unroll
    for (int ni = 0; ni < 4; ++ni) acc[mi][ni] = (f32x4){0.f, 0.f, 0.f, 0.f};

  STAGE2(0, 0);
  const int lrow = lane & 15, lk = (lane >> 4) * 8;
#pragma unroll 1
  for (int ks = 0; ks < 64; ++ks) {
    const int curb = ks & 1;
    if (ks < 63) {
      STAGE2(curb ^ 1, ks + 1);
      asm volatile("s_waitcnt vmcnt(8)" ::: "memory");
    } else {
      asm volatile("s_waitcnt vmcnt(0)" ::: "memory");
    }
    membar(); __builtin_amdgcn_s_barrier(); membar();
    const u16* A = As[curb];
    const u16* B = Bs[curb];
#pragma unroll
    for (int kk = 0; kk < 2; ++kk) {
      bf16x8 af[4], bfr[4];
#pragma unroll
      for (int mi = 0; mi < 4; ++mi)
        af[mi] = *(const bf16x8*)&A[(wm * 64 + mi * 16 + lrow) * 64 + kk * 32 + lk];
#pragma unroll
      for (int ni = 0; ni < 4; ++ni)
        bfr[ni] = *(const bf16x8*)&B[(wn * 64 + ni * 16 + lrow) * 64 + kk * 32 + lk];
#pragma unroll
      for (int mi = 0; mi < 4; ++mi)
#pragma unroll
        for (int ni = 0; ni < 4; ++ni)
          acc[mi][ni] = __builtin_amdgcn_mfma_f32_16x16x32_bf16(af[mi], bfr[ni], acc[mi][ni], 0, 0, 0);
    }
    membar(); __builtin_amdgcn_s_barrier(); membar();
  }

#pragma unroll
  for (int mi = 0; mi < 4; ++mi) {
    int rb = wm * 64 + mi * 16 + (lane >> 4) * 4;
#pragma unroll
    for (int j = 0; j < 4; ++j) {
      int row = m0 + rb + j;
      if (row < Me) {
        int aid = tokl[offs + row];
#pragma unroll
        for (int ni = 0; ni < 4; ++ni) {
          int col = n0 + wn * 64 + ni * 16 + (lane & 15);
          buf[(size_t)aid * HD + col] = acc[mi][ni][j];
        }
      }
    }
  }
#undef STAGE2
}

// ---- final: out[t] = ewt[2t]*buf[2t] + ewt[2t+1]*buf[2t+1] ----
__global__ void k_final(const float* __restrict__ buf, const float* __restrict__ ewt,
                        float* __restrict__ out) {
  size_t idx = (size_t)blockIdx.x * 256 + threadIdx.x;  // float4 units
  int tok = (int)(idx >> 8);
  int c4 = (int)(idx & 255);
  const float4* b0 = (const float4*)(buf + (size_t)(2 * tok) * HD) + c4;
  const float4* b1 = (const float4*)(buf + (size_t)(2 * tok + 1) * HD) + c4;
  float w0 = ewt[2 * tok], w1 = ewt[2 * tok + 1];
  float4 a = *b0, b = *b1;
  float4 r = {w0 * a.x + w1 * b.x, w0 * a.y + w1 * b.y,
              w0 * a.z + w1 * b.z, w0 * a.w + w1 * b.w};
  ((float4*)(out + (size_t)tok * HD))[c4] = r;
}

extern "C" void kernel_launch(void* const* d_in, const int* in_sizes, int n_in,
                              void* d_out, int out_size, void* d_ws, size_t ws_size,
                              hipStream_t stream) {
  const float* x    = (const float*)d_in[0];
  const int*   eidx = (const int*)d_in[1];
  const float* ewt  = (const float*)d_in[2];
  const float* gate = (const float*)d_in[3];
  const float* up   = (const float*)d_in[4];
  const float* down = (const float*)d_in[5];
  float* out = (float*)d_out;
  char* ws = (char*)d_ws;

  // layout (total 276,857,088 B <= proven ws budget from rounds 1-2):
  constexpr size_t OFF_INTERM = 0;           // 64 MiB bf16 interm
  constexpr size_t OFF_XB     = 67108864;    // 8 MiB bf16 x
  constexpr size_t OFF_META   = 75497472;    // offsets
  constexpr size_t OFF_TOK    = 75497728;    // 32 KiB assignment ids
  constexpr size_t OFF_WD     = 75530496;    // 64 MiB bf16 down
  constexpr size_t OFF_WG     = 142639360;   // 64 MiB bf16 gate; buf aliases (32 MiB)
  constexpr size_t OFF_WU     = 209748224;   // 64 MiB bf16 up

  u16* interm  = (u16*)(ws + OFF_INTERM);
  u16* xb      = (u16*)(ws + OFF_XB);
  int* offsets = (int*)(ws + OFF_META);
  int* tokl    = (int*)(ws + OFF_TOK);
  u16* wd      = (u16*)(ws + OFF_WD);
  u16* wg      = (u16*)(ws + OFF_WG);
  u16* wu      = (u16*)(ws + OFF_WU);
  float* buf   = (float*)(ws + OFF_WG);      // alias: wg dead after k_g1

  k_pre<<<dim3(34816), dim3(256), 0, stream>>>(x, gate, up, xb, wg, wu);
  k_meta<<<dim3(1), dim3(1024), 0, stream>>>(eidx, offsets, tokl);
  k_g1<<<dim3(49152), dim3(256), 0, stream>>>(xb, wg, wu, down, wd, offsets, tokl, interm);
  k_g2<<<dim3(8, 64, 8), dim3(256), 0, stream>>>(interm, wd, offsets, tokl, buf);
  k_final<<<dim3(4096), dim3(256), 0, stream>>>(buf, ewt, out);
}

// Round 4
// 553.537 us; speedup vs baseline: 1.8786x; 1.8786x over previous
//
#include <hip/hip_runtime.h>
#include <hip/hip_bf16.h>
#include <cstdint>

#define HD 1024
#define ID 4096
#define NE 8
#define NTOK 4096
#define NASS 8192
#define NWL 72

typedef unsigned short u16;
typedef __attribute__((ext_vector_type(8))) __bf16 bf16x8;
typedef __attribute__((ext_vector_type(4))) float f32x4;

__device__ __forceinline__ void async16(void* lds, const void* g) {
  __builtin_amdgcn_global_load_lds(
      (const __attribute__((address_space(1))) uint32_t*)g,
      (__attribute__((address_space(3))) uint32_t*)lds, 16, 0, 0);
}

__device__ __forceinline__ u16 f2b(float f) {
  __bf16 h = (__bf16)f;
  return __builtin_bit_cast(u16, h);
}

__device__ __forceinline__ bf16x8 cvt8(const float* p) {
  const float4* q = (const float4*)p;
  float4 a = q[0], b = q[1];
  bf16x8 v;
  v[0] = (__bf16)a.x; v[1] = (__bf16)a.y; v[2] = (__bf16)a.z; v[3] = (__bf16)a.w;
  v[4] = (__bf16)b.x; v[5] = (__bf16)b.y; v[6] = (__bf16)b.z; v[7] = (__bf16)b.w;
  return v;
}

// ---- prep: all fp32->bf16 conversions in one BW-bound pass ----
// x (2048 blocks), gate (16384), up (16384), down (16384)
__global__ void k_pre(const float* __restrict__ x, const float* __restrict__ gate,
                      const float* __restrict__ up, const float* __restrict__ down,
                      u16* __restrict__ xb, u16* __restrict__ wg,
                      u16* __restrict__ wu, u16* __restrict__ wd) {
  int bid = blockIdx.x, t = threadIdx.x;
  const float* src; u16* dst; size_t base;
  if (bid < 2048)        { src = x;    dst = xb; base = (size_t)bid * 256; }
  else if (bid < 18432)  { src = gate; dst = wg; base = (size_t)(bid - 2048) * 256; }
  else if (bid < 34816)  { src = up;   dst = wu; base = (size_t)(bid - 18432) * 256; }
  else                   { src = down; dst = wd; base = (size_t)(bid - 34816) * 256; }
  size_t i8 = (base + t) * 8;
  *(bf16x8*)(dst + i8) = cvt8(src + i8);
}

// ---- fused count + scan + place + worklist (single block) ----
__global__ void k_meta(const int* __restrict__ eidx, int* __restrict__ offsets,
                       int* __restrict__ wl, int* __restrict__ tokl) {
  __shared__ int cnt[NE], offs_s[NE + 1], cur[NE];
  int t = threadIdx.x;
  if (t < NE) cnt[t] = 0;
  __syncthreads();
  for (int i = t; i < NASS; i += 1024) atomicAdd(&cnt[eidx[i]], 1);
  __syncthreads();
  if (t == 0) {
    int s = 0;
    for (int e = 0; e < NE; ++e) { offs_s[e] = s; s += cnt[e]; }
    offs_s[NE] = s;
    int w = 0;
    for (int e = 0; e < NE; ++e)
      for (int mt = 0; mt * 128 < cnt[e]; ++mt) wl[w++] = (e << 16) | mt;
    for (; w < NWL; ++w) wl[w] = -1;
  }
  if (t < NE) cur[t] = 0;
  __syncthreads();
  for (int i = t; i < NASS; i += 1024) {
    int e = eidx[i];
    int p = atomicAdd(&cur[e], 1);
    tokl[offs_s[e] + p] = i;   // assignment id (token = i>>1)
  }
  if (t <= NE) offsets[t] = offs_s[t];
}

// ---- GEMM1: interm = silu(X@G^T)*(X@U^T); round-2 proven structure ----
// BM=128, BN=64 dual (gate+up), BK=64, 4 waves, 32KB LDS, single-buffer
__global__ __launch_bounds__(256) void k_g1(
    const u16* __restrict__ xb, const u16* __restrict__ wg, const u16* __restrict__ wu,
    const int* __restrict__ offsets, const int* __restrict__ wl,
    const int* __restrict__ tokl, u16* __restrict__ interm) {
  const int wle = wl[blockIdx.y];
  if (wle < 0) return;
  const int e = wle >> 16;
  const int m0 = (wle & 0xffff) << 7;
  const int offs = offsets[e];
  const int Me = offsets[e + 1] - offs;
  const int n0 = blockIdx.x * 64;
  const int t = threadIdx.x, lane = t & 63, wv = t >> 6;
  const int wm = wv & 1, wn = wv >> 1;

  __shared__ __align__(16) u16 As[128 * 64];
  __shared__ __align__(16) u16 Bg[64 * 64];
  __shared__ __align__(16) u16 Bu[64 * 64];

  const u16* asrc[4];
#pragma unroll
  for (int p = 0; p < 4; ++p) {
    int c = p * 256 + t;
    int r = c >> 3, c8 = c & 7;
    int row = m0 + r; if (row > Me - 1) row = Me - 1;
    asrc[p] = xb + (size_t)(tokl[offs + row] >> 1) * HD + c8 * 8;
  }
  const u16 *bgsrc[2], *busrc[2];
#pragma unroll
  for (int q = 0; q < 2; ++q) {
    int c = q * 256 + t;
    int r = c >> 3, c8 = c & 7;
    size_t boff = ((size_t)e * ID + n0 + r) * HD + c8 * 8;
    bgsrc[q] = wg + boff;
    busrc[q] = wu + boff;
  }

  f32x4 accg[4][2], accu[4][2];
#pragma unroll
  for (int mi = 0; mi < 4; ++mi)
#pragma unroll
    for (int ni = 0; ni < 2; ++ni) {
      accg[mi][ni] = (f32x4){0.f, 0.f, 0.f, 0.f};
      accu[mi][ni] = (f32x4){0.f, 0.f, 0.f, 0.f};
    }

  const int lrow = lane & 15, lk = (lane >> 4) * 8;
#pragma unroll 1
  for (int ks = 0; ks < HD / 64; ++ks) {
    __syncthreads();
#pragma unroll
    for (int p = 0; p < 4; ++p)
      async16((char*)As + (p * 256 + wv * 64) * 16, asrc[p]);
#pragma unroll
    for (int q = 0; q < 2; ++q) {
      async16((char*)Bg + (q * 256 + wv * 64) * 16, bgsrc[q]);
      async16((char*)Bu + (q * 256 + wv * 64) * 16, busrc[q]);
    }
    __syncthreads();
#pragma unroll
    for (int kk = 0; kk < 2; ++kk) {
      bf16x8 af[4], bg[2], bu[2];
#pragma unroll
      for (int mi = 0; mi < 4; ++mi)
        af[mi] = *(const bf16x8*)&As[(wm * 64 + mi * 16 + lrow) * 64 + kk * 32 + lk];
#pragma unroll
      for (int ni = 0; ni < 2; ++ni) {
        bg[ni] = *(const bf16x8*)&Bg[(wn * 32 + ni * 16 + lrow) * 64 + kk * 32 + lk];
        bu[ni] = *(const bf16x8*)&Bu[(wn * 32 + ni * 16 + lrow) * 64 + kk * 32 + lk];
      }
#pragma unroll
      for (int mi = 0; mi < 4; ++mi)
#pragma unroll
        for (int ni = 0; ni < 2; ++ni) {
          accg[mi][ni] = __builtin_amdgcn_mfma_f32_16x16x32_bf16(af[mi], bg[ni], accg[mi][ni], 0, 0, 0);
          accu[mi][ni] = __builtin_amdgcn_mfma_f32_16x16x32_bf16(af[mi], bu[ni], accu[mi][ni], 0, 0, 0);
        }
    }
#pragma unroll
    for (int p = 0; p < 4; ++p) asrc[p] += 64;
    bgsrc[0] += 64; bgsrc[1] += 64; busrc[0] += 64; busrc[1] += 64;
  }

#pragma unroll
  for (int mi = 0; mi < 4; ++mi) {
    int rb = wm * 64 + mi * 16 + (lane >> 4) * 4;
#pragma unroll
    for (int ni = 0; ni < 2; ++ni) {
      int col = n0 + wn * 32 + ni * 16 + (lane & 15);
#pragma unroll
      for (int j = 0; j < 4; ++j) {
        int row = m0 + rb + j;
        if (row < Me) {
          float g = accg[mi][ni][j], u = accu[mi][ni][j];
          float s = g / (1.f + __expf(-g));
          interm[(size_t)(offs + row) * ID + col] = f2b(s * u);
        }
      }
    }
  }
}

// ---- GEMM2: buf[aid,:] = interm @ D^T (raw); round-2 structure, 128x128 ----
__global__ __launch_bounds__(256) void k_g2(
    const u16* __restrict__ interm, const u16* __restrict__ wd,
    const int* __restrict__ offsets, const int* __restrict__ wl,
    const int* __restrict__ tokl, float* __restrict__ buf) {
  const int wle = wl[blockIdx.y];
  if (wle < 0) return;
  const int e = wle >> 16;
  const int m0 = (wle & 0xffff) << 7;
  const int offs = offsets[e];
  const int Me = offsets[e + 1] - offs;
  const int n0 = blockIdx.x * 128;
  const int t = threadIdx.x, lane = t & 63, wv = t >> 6;
  const int wm = wv & 1, wn = wv >> 1;

  __shared__ __align__(16) u16 As[128 * 64];
  __shared__ __align__(16) u16 Bs[128 * 64];

  const u16* asrc[4];
#pragma unroll
  for (int p = 0; p < 4; ++p) {
    int c = p * 256 + t;
    int r = c >> 3, c8 = c & 7;
    int row = m0 + r; if (row > Me - 1) row = Me - 1;
    asrc[p] = interm + (size_t)(offs + row) * ID + c8 * 8;
  }
  const u16* bsrc[4];
#pragma unroll
  for (int p = 0; p < 4; ++p) {
    int c = p * 256 + t;
    int r = c >> 3, c8 = c & 7;
    bsrc[p] = wd + ((size_t)e * HD + n0 + r) * ID + c8 * 8;
  }

  f32x4 acc[4][4];
#pragma unroll
  for (int mi = 0; mi < 4; ++mi)
#pragma unroll
    for (int ni = 0; ni < 4; ++ni) acc[mi][ni] = (f32x4){0.f, 0.f, 0.f, 0.f};

  const int lrow = lane & 15, lk = (lane >> 4) * 8;
#pragma unroll 1
  for (int ks = 0; ks < ID / 64; ++ks) {
    __syncthreads();
#pragma unroll
    for (int p = 0; p < 4; ++p) {
      async16((char*)As + (p * 256 + wv * 64) * 16, asrc[p]);
      async16((char*)Bs + (p * 256 + wv * 64) * 16, bsrc[p]);
    }
    __syncthreads();
#pragma unroll
    for (int kk = 0; kk < 2; ++kk) {
      bf16x8 af[4], bfr[4];
#pragma unroll
      for (int mi = 0; mi < 4; ++mi)
        af[mi] = *(const bf16x8*)&As[(wm * 64 + mi * 16 + lrow) * 64 + kk * 32 + lk];
#pragma unroll
      for (int ni = 0; ni < 4; ++ni)
        bfr[ni] = *(const bf16x8*)&Bs[(wn * 64 + ni * 16 + lrow) * 64 + kk * 32 + lk];
#pragma unroll
      for (int mi = 0; mi < 4; ++mi)
#pragma unroll
        for (int ni = 0; ni < 4; ++ni)
          acc[mi][ni] = __builtin_amdgcn_mfma_f32_16x16x32_bf16(af[mi], bfr[ni], acc[mi][ni], 0, 0, 0);
    }
#pragma unroll
    for (int p = 0; p < 4; ++p) { asrc[p] += 64; bsrc[p] += 64; }
  }

#pragma unroll
  for (int mi = 0; mi < 4; ++mi) {
    int rb = wm * 64 + mi * 16 + (lane >> 4) * 4;
#pragma unroll
    for (int j = 0; j < 4; ++j) {
      int row = m0 + rb + j;
      if (row < Me) {
        int aid = tokl[offs + row];
#pragma unroll
        for (int ni = 0; ni < 4; ++ni) {
          int col = n0 + wn * 64 + ni * 16 + (lane & 15);
          buf[(size_t)aid * HD + col] = acc[mi][ni][j];
        }
      }
    }
  }
}

// ---- final: out[t] = ewt[2t]*buf[2t] + ewt[2t+1]*buf[2t+1] ----
__global__ void k_final(const float* __restrict__ buf, const float* __restrict__ ewt,
                        float* __restrict__ out) {
  size_t idx = (size_t)blockIdx.x * 256 + threadIdx.x;  // float4 units
  int tok = (int)(idx >> 8);
  int c4 = (int)(idx & 255);
  const float4* b0 = (const float4*)(buf + (size_t)(2 * tok) * HD) + c4;
  const float4* b1 = (const float4*)(buf + (size_t)(2 * tok + 1) * HD) + c4;
  float w0 = ewt[2 * tok], w1 = ewt[2 * tok + 1];
  float4 a = *b0, b = *b1;
  float4 r = {w0 * a.x + w1 * b.x, w0 * a.y + w1 * b.y,
              w0 * a.z + w1 * b.z, w0 * a.w + w1 * b.w};
  ((float4*)(out + (size_t)tok * HD))[c4] = r;
}

extern "C" void kernel_launch(void* const* d_in, const int* in_sizes, int n_in,
                              void* d_out, int out_size, void* d_ws, size_t ws_size,
                              hipStream_t stream) {
  const float* x    = (const float*)d_in[0];
  const int*   eidx = (const int*)d_in[1];
  const float* ewt  = (const float*)d_in[2];
  const float* gate = (const float*)d_in[3];
  const float* up   = (const float*)d_in[4];
  const float* down = (const float*)d_in[5];
  float* out = (float*)d_out;
  char* ws = (char*)d_ws;

  // layout (total 276,857,856 B <= proven budget from rounds 1-3):
  constexpr size_t OFF_INTERM = 0;           // 64 MiB bf16 interm
  constexpr size_t OFF_XB     = 67108864;    // 8 MiB bf16 x
  constexpr size_t OFF_META   = 75497472;    // offsets @ +0, wl @ +64
  constexpr size_t OFF_TOK    = 75498496;    // 32 KiB assignment ids
  constexpr size_t OFF_WD     = 75531264;    // 64 MiB bf16 down
  constexpr size_t OFF_WG     = 142640128;   // 64 MiB bf16 gate; buf aliases (32 MiB)
  constexpr size_t OFF_WU     = 209748992;   // 64 MiB bf16 up

  u16* interm  = (u16*)(ws + OFF_INTERM);
  u16* xb      = (u16*)(ws + OFF_XB);
  int* offsets = (int*)(ws + OFF_META);
  int* wl      = (int*)(ws + OFF_META + 64);
  int* tokl    = (int*)(ws + OFF_TOK);
  u16* wd      = (u16*)(ws + OFF_WD);
  u16* wg      = (u16*)(ws + OFF_WG);
  u16* wu      = (u16*)(ws + OFF_WU);
  float* buf   = (float*)(ws + OFF_WG);      // alias: wg dead after k_g1

  k_pre<<<dim3(51200), dim3(256), 0, stream>>>(x, gate, up, down, xb, wg, wu, wd);
  k_meta<<<dim3(1), dim3(1024), 0, stream>>>(eidx, offsets, wl, tokl);
  k_g1<<<dim3(ID / 64, NWL), dim3(256), 0, stream>>>(xb, wg, wu, offsets, wl, tokl, interm);
  k_g2<<<dim3(HD / 128, NWL), dim3(256), 0, stream>>>(interm, wd, offsets, wl, tokl, buf);
  k_final<<<dim3(4096), dim3(256), 0, stream>>>(buf, ewt, out);
}

// Round 5
// 483.935 us; speedup vs baseline: 2.1488x; 1.1438x over previous
//
#include <hip/hip_runtime.h>
#include <hip/hip_bf16.h>
#include <cstdint>

#define HD 1024
#define ID 4096
#define NE 8
#define NTOK 4096
#define NASS 8192
#define NWL 72

typedef unsigned short u16;
typedef __attribute__((ext_vector_type(8))) __bf16 bf16x8;
typedef __attribute__((ext_vector_type(4))) float f32x4;

__device__ __forceinline__ void async16(void* lds, const void* g) {
  __builtin_amdgcn_global_load_lds(
      (const __attribute__((address_space(1))) uint32_t*)g,
      (__attribute__((address_space(3))) uint32_t*)lds, 16, 0, 0);
}

__device__ __forceinline__ u16 f2b(float f) {
  __bf16 h = (__bf16)f;
  return __builtin_bit_cast(u16, h);
}

__device__ __forceinline__ bf16x8 cvt8(const float* p) {
  const float4* q = (const float4*)p;
  float4 a = q[0], b = q[1];
  bf16x8 v;
  v[0] = (__bf16)a.x; v[1] = (__bf16)a.y; v[2] = (__bf16)a.z; v[3] = (__bf16)a.w;
  v[4] = (__bf16)b.x; v[5] = (__bf16)b.y; v[6] = (__bf16)b.z; v[7] = (__bf16)b.w;
  return v;
}

// ---- prep: x, gate, up fp32->bf16 (down handled inside k_g1) ----
__global__ void k_pre(const float* __restrict__ x, const float* __restrict__ gate,
                      const float* __restrict__ up, u16* __restrict__ xb,
                      u16* __restrict__ wg, u16* __restrict__ wu) {
  int bid = blockIdx.x, t = threadIdx.x;
  const float* src; u16* dst; size_t base;
  if (bid < 2048)        { src = x;    dst = xb; base = (size_t)bid * 256; }
  else if (bid < 18432)  { src = gate; dst = wg; base = (size_t)(bid - 2048) * 256; }
  else                   { src = up;   dst = wu; base = (size_t)(bid - 18432) * 256; }
  size_t i8 = (base + t) * 8;
  *(bf16x8*)(dst + i8) = cvt8(src + i8);
}

// ---- fused count + scan + place + worklist (single block) ----
__global__ void k_meta(const int* __restrict__ eidx, int* __restrict__ offsets,
                       int* __restrict__ wl, int* __restrict__ tokl) {
  __shared__ int cnt[NE], offs_s[NE + 1], cur[NE];
  int t = threadIdx.x;
  if (t < NE) cnt[t] = 0;
  __syncthreads();
  for (int i = t; i < NASS; i += 1024) atomicAdd(&cnt[eidx[i]], 1);
  __syncthreads();
  if (t == 0) {
    int s = 0;
    for (int e = 0; e < NE; ++e) { offs_s[e] = s; s += cnt[e]; }
    offs_s[NE] = s;
    int w = 0;
    for (int e = 0; e < NE; ++e)
      for (int mt = 0; mt * 128 < cnt[e]; ++mt) wl[w++] = (e << 16) | mt;
    for (; w < NWL; ++w) wl[w] = -1;
  }
  if (t < NE) cur[t] = 0;
  __syncthreads();
  for (int i = t; i < NASS; i += 1024) {
    int e = eidx[i];
    int p = atomicAdd(&cur[e], 1);
    tokl[offs_s[e] + p] = i;   // assignment id (token = i>>1)
  }
  if (t <= NE) offsets[t] = offs_s[t];
}

// ---- GEMM1: interm = silu(X@G^T)*(X@U^T); BM=128 BN=128 dual, BK=64 ----
// blocks bx>=32 instead convert down fp32->bf16 (hidden under gemm compute)
__global__ __launch_bounds__(256, 2) void k_g1(
    const u16* __restrict__ xb, const u16* __restrict__ wg, const u16* __restrict__ wu,
    const float* __restrict__ down, u16* __restrict__ wd,
    const int* __restrict__ offsets, const int* __restrict__ wl,
    const int* __restrict__ tokl, u16* __restrict__ interm) {
  const int bx = blockIdx.x;
  const int t = threadIdx.x;
  if (bx >= 32) {                     // down-proj conversion lane
    int cid = (bx - 32) + 32 * (int)blockIdx.y;
    if (cid < 2048) {
#pragma unroll
      for (int l = 0; l < 8; ++l) {
        size_t i8 = (((size_t)cid * 8 + l) * 256 + t) * 8;
        *(bf16x8*)(wd + i8) = cvt8(down + i8);
      }
    }
    return;
  }
  const int wle = wl[blockIdx.y];
  if (wle < 0) return;
  const int e = wle >> 16;
  const int m0 = (wle & 0xffff) << 7;
  const int offs = offsets[e];
  const int Me = offsets[e + 1] - offs;
  const int n0 = bx * 128;
  const int lane = t & 63, wv = t >> 6;
  const int wm = wv & 1, wn = wv >> 1;

  __shared__ __align__(16) u16 As[128 * 64];
  __shared__ __align__(16) u16 Bg[128 * 64];
  __shared__ __align__(16) u16 Bu[128 * 64];

  const u16* asrc[4];
#pragma unroll
  for (int p = 0; p < 4; ++p) {
    int c = p * 256 + t;
    int r = c >> 3, c8 = c & 7;
    int row = m0 + r; if (row > Me - 1) row = Me - 1;
    asrc[p] = xb + (size_t)(tokl[offs + row] >> 1) * HD + c8 * 8;
  }
  const u16 *bgsrc[4], *busrc[4];
#pragma unroll
  for (int p = 0; p < 4; ++p) {
    int c = p * 256 + t;
    int r = c >> 3, c8 = c & 7;
    size_t boff = ((size_t)e * ID + n0 + r) * HD + c8 * 8;
    bgsrc[p] = wg + boff;
    busrc[p] = wu + boff;
  }

  f32x4 accg[4][4], accu[4][4];
#pragma unroll
  for (int mi = 0; mi < 4; ++mi)
#pragma unroll
    for (int ni = 0; ni < 4; ++ni) {
      accg[mi][ni] = (f32x4){0.f, 0.f, 0.f, 0.f};
      accu[mi][ni] = (f32x4){0.f, 0.f, 0.f, 0.f};
    }

  const int lrow = lane & 15, lk = (lane >> 4) * 8;
#pragma unroll 1
  for (int ks = 0; ks < HD / 64; ++ks) {
    __syncthreads();
#pragma unroll
    for (int p = 0; p < 4; ++p) {
      async16((char*)As + (p * 256 + wv * 64) * 16, asrc[p]);
      async16((char*)Bg + (p * 256 + wv * 64) * 16, bgsrc[p]);
      async16((char*)Bu + (p * 256 + wv * 64) * 16, busrc[p]);
    }
    __syncthreads();
#pragma unroll
    for (int kk = 0; kk < 2; ++kk) {
      bf16x8 af[4], bg[4], bu[4];
#pragma unroll
      for (int mi = 0; mi < 4; ++mi)
        af[mi] = *(const bf16x8*)&As[(wm * 64 + mi * 16 + lrow) * 64 + kk * 32 + lk];
#pragma unroll
      for (int ni = 0; ni < 4; ++ni) {
        bg[ni] = *(const bf16x8*)&Bg[(wn * 64 + ni * 16 + lrow) * 64 + kk * 32 + lk];
        bu[ni] = *(const bf16x8*)&Bu[(wn * 64 + ni * 16 + lrow) * 64 + kk * 32 + lk];
      }
#pragma unroll
      for (int mi = 0; mi < 4; ++mi)
#pragma unroll
        for (int ni = 0; ni < 4; ++ni) {
          accg[mi][ni] = __builtin_amdgcn_mfma_f32_16x16x32_bf16(af[mi], bg[ni], accg[mi][ni], 0, 0, 0);
          accu[mi][ni] = __builtin_amdgcn_mfma_f32_16x16x32_bf16(af[mi], bu[ni], accu[mi][ni], 0, 0, 0);
        }
    }
#pragma unroll
    for (int p = 0; p < 4; ++p) { asrc[p] += 64; bgsrc[p] += 64; busrc[p] += 64; }
  }

#pragma unroll
  for (int mi = 0; mi < 4; ++mi) {
    int rb = wm * 64 + mi * 16 + (lane >> 4) * 4;
#pragma unroll
    for (int ni = 0; ni < 4; ++ni) {
      int col = n0 + wn * 64 + ni * 16 + (lane & 15);
#pragma unroll
      for (int j = 0; j < 4; ++j) {
        int row = m0 + rb + j;
        if (row < Me) {
          float g = accg[mi][ni][j], u = accu[mi][ni][j];
          float s = g / (1.f + __expf(-g));
          interm[(size_t)(offs + row) * ID + col] = f2b(s * u);
        }
      }
    }
  }
}

// ---- GEMM2: buf[aid,:] = interm @ D^T (raw); 128x128, single-buffer ----
__global__ __launch_bounds__(256) void k_g2(
    const u16* __restrict__ interm, const u16* __restrict__ wd,
    const int* __restrict__ offsets, const int* __restrict__ wl,
    const int* __restrict__ tokl, float* __restrict__ buf) {
  const int wle = wl[blockIdx.y];
  if (wle < 0) return;
  const int e = wle >> 16;
  const int m0 = (wle & 0xffff) << 7;
  const int offs = offsets[e];
  const int Me = offsets[e + 1] - offs;
  const int n0 = blockIdx.x * 128;
  const int t = threadIdx.x, lane = t & 63, wv = t >> 6;
  const int wm = wv & 1, wn = wv >> 1;

  __shared__ __align__(16) u16 As[128 * 64];
  __shared__ __align__(16) u16 Bs[128 * 64];

  const u16* asrc[4];
#pragma unroll
  for (int p = 0; p < 4; ++p) {
    int c = p * 256 + t;
    int r = c >> 3, c8 = c & 7;
    int row = m0 + r; if (row > Me - 1) row = Me - 1;
    asrc[p] = interm + (size_t)(offs + row) * ID + c8 * 8;
  }
  const u16* bsrc[4];
#pragma unroll
  for (int p = 0; p < 4; ++p) {
    int c = p * 256 + t;
    int r = c >> 3, c8 = c & 7;
    bsrc[p] = wd + ((size_t)e * HD + n0 + r) * ID + c8 * 8;
  }

  f32x4 acc[4][4];
#pragma unroll
  for (int mi = 0; mi < 4; ++mi)
#pragma unroll
    for (int ni = 0; ni < 4; ++ni) acc[mi][ni] = (f32x4){0.f, 0.f, 0.f, 0.f};

  const int lrow = lane & 15, lk = (lane >> 4) * 8;
#pragma unroll 1
  for (int ks = 0; ks < ID / 64; ++ks) {
    __syncthreads();
#pragma unroll
    for (int p = 0; p < 4; ++p) {
      async16((char*)As + (p * 256 + wv * 64) * 16, asrc[p]);
      async16((char*)Bs + (p * 256 + wv * 64) * 16, bsrc[p]);
    }
    __syncthreads();
#pragma unroll
    for (int kk = 0; kk < 2; ++kk) {
      bf16x8 af[4], bfr[4];
#pragma unroll
      for (int mi = 0; mi < 4; ++mi)
        af[mi] = *(const bf16x8*)&As[(wm * 64 + mi * 16 + lrow) * 64 + kk * 32 + lk];
#pragma unroll
      for (int ni = 0; ni < 4; ++ni)
        bfr[ni] = *(const bf16x8*)&Bs[(wn * 64 + ni * 16 + lrow) * 64 + kk * 32 + lk];
#pragma unroll
      for (int mi = 0; mi < 4; ++mi)
#pragma unroll
        for (int ni = 0; ni < 4; ++ni)
          acc[mi][ni] = __builtin_amdgcn_mfma_f32_16x16x32_bf16(af[mi], bfr[ni], acc[mi][ni], 0, 0, 0);
    }
#pragma unroll
    for (int p = 0; p < 4; ++p) { asrc[p] += 64; bsrc[p] += 64; }
  }

#pragma unroll
  for (int mi = 0; mi < 4; ++mi) {
    int rb = wm * 64 + mi * 16 + (lane >> 4) * 4;
#pragma unroll
    for (int j = 0; j < 4; ++j) {
      int row = m0 + rb + j;
      if (row < Me) {
        int aid = tokl[offs + row];
#pragma unroll
        for (int ni = 0; ni < 4; ++ni) {
          int col = n0 + wn * 64 + ni * 16 + (lane & 15);
          buf[(size_t)aid * HD + col] = acc[mi][ni][j];
        }
      }
    }
  }
}

// ---- final: out[t] = ewt[2t]*buf[2t] + ewt[2t+1]*buf[2t+1] ----
__global__ void k_final(const float* __restrict__ buf, const float* __restrict__ ewt,
                        float* __restrict__ out) {
  size_t idx = (size_t)blockIdx.x * 256 + threadIdx.x;  // float4 units
  int tok = (int)(idx >> 8);
  int c4 = (int)(idx & 255);
  const float4* b0 = (const float4*)(buf + (size_t)(2 * tok) * HD) + c4;
  const float4* b1 = (const float4*)(buf + (size_t)(2 * tok + 1) * HD) + c4;
  float w0 = ewt[2 * tok], w1 = ewt[2 * tok + 1];
  float4 a = *b0, b = *b1;
  float4 r = {w0 * a.x + w1 * b.x, w0 * a.y + w1 * b.y,
              w0 * a.z + w1 * b.z, w0 * a.w + w1 * b.w};
  ((float4*)(out + (size_t)tok * HD))[c4] = r;
}

extern "C" void kernel_launch(void* const* d_in, const int* in_sizes, int n_in,
                              void* d_out, int out_size, void* d_ws, size_t ws_size,
                              hipStream_t stream) {
  const float* x    = (const float*)d_in[0];
  const int*   eidx = (const int*)d_in[1];
  const float* ewt  = (const float*)d_in[2];
  const float* gate = (const float*)d_in[3];
  const float* up   = (const float*)d_in[4];
  const float* down = (const float*)d_in[5];
  float* out = (float*)d_out;
  char* ws = (char*)d_ws;

  // layout (total 276,857,856 B <= proven budget from rounds 1-4):
  constexpr size_t OFF_INTERM = 0;           // 64 MiB bf16 interm
  constexpr size_t OFF_XB     = 67108864;    // 8 MiB bf16 x
  constexpr size_t OFF_META   = 75497472;    // offsets @ +0, wl @ +64
  constexpr size_t OFF_TOK    = 75498496;    // 32 KiB assignment ids
  constexpr size_t OFF_WD     = 75531264;    // 64 MiB bf16 down
  constexpr size_t OFF_WG     = 142640128;   // 64 MiB bf16 gate; buf aliases (32 MiB)
  constexpr size_t OFF_WU     = 209748992;   // 64 MiB bf16 up

  u16* interm  = (u16*)(ws + OFF_INTERM);
  u16* xb      = (u16*)(ws + OFF_XB);
  int* offsets = (int*)(ws + OFF_META);
  int* wl      = (int*)(ws + OFF_META + 64);
  int* tokl    = (int*)(ws + OFF_TOK);
  u16* wd      = (u16*)(ws + OFF_WD);
  u16* wg      = (u16*)(ws + OFF_WG);
  u16* wu      = (u16*)(ws + OFF_WU);
  float* buf   = (float*)(ws + OFF_WG);      // alias: wg dead after k_g1

  k_pre<<<dim3(34816), dim3(256), 0, stream>>>(x, gate, up, xb, wg, wu);
  k_meta<<<dim3(1), dim3(1024), 0, stream>>>(eidx, offsets, wl, tokl);
  k_g1<<<dim3(64, NWL), dim3(256), 0, stream>>>(xb, wg, wu, down, wd, offsets, wl, tokl, interm);
  k_g2<<<dim3(HD / 128, NWL), dim3(256), 0, stream>>>(interm, wd, offsets, wl, tokl, buf);
  k_final<<<dim3(4096), dim3(256), 0, stream>>>(buf, ewt, out);
}